// Round 8
// baseline (298.516 us; speedup 1.0000x reference)
//
#include <hip/hip_runtime.h>

#define NN 50000
#define NE 1500000
#define DD 128
#define NRANGE ((NN + 255) / 256)      // 196 dst-ranges of 256 nodes
#define NBUCK (3 * NRANGE)             // 588 (rel, range) buckets
#define BINB 256                       // binning blocks
#define CHUNK ((NE + BINB - 1) / BINB) // 5860 edges per binning block
#define NH2 (NBUCK * BINB)             // 150528 hist2 entries

typedef __attribute__((ext_vector_type(8))) short short8;
typedef __attribute__((ext_vector_type(4))) float f32x4;

__device__ __forceinline__ ushort f2b(float x) {
    uint u = __float_as_uint(x);
    u += 0x7FFFu + ((u >> 16) & 1u);
    return (ushort)(u >> 16);
}
__device__ __forceinline__ float b2f(ushort b) {
    return __uint_as_float(((uint)b) << 16);
}

// ---------------- scan helpers ----------------
__global__ __launch_bounds__(256) void scan_block(
    const int* __restrict__ cnt, int* __restrict__ ptr, int* __restrict__ part, int n)
{
    __shared__ int s[256];
    int i = blockIdx.x * 256 + threadIdx.x;
    int v = (i < n) ? cnt[i] : 0;
    s[threadIdx.x] = v;
    __syncthreads();
    #pragma unroll
    for (int off = 1; off < 256; off <<= 1) {
        int t = (threadIdx.x >= off) ? s[threadIdx.x - off] : 0;
        __syncthreads();
        s[threadIdx.x] += t;
        __syncthreads();
    }
    if (i < n) ptr[i] = s[threadIdx.x] - v;
    if (threadIdx.x == 255) part[blockIdx.x] = s[255];
}

__global__ void scan_partials(int* __restrict__ part, int nb)
{
    int lane = threadIdx.x;
    int run = 0;
    for (int base = 0; base < nb; base += 64) {
        int i = base + lane;
        int v = (i < nb) ? part[i] : 0;
        int x = v;
        #pragma unroll
        for (int off = 1; off < 64; off <<= 1) {
            int t = __shfl_up(x, off);
            if (lane >= off) x += t;
        }
        if (i < nb) part[i] = run + x - v;
        run += __shfl(x, 63);
    }
}

__global__ __launch_bounds__(256) void scan_add(
    int* __restrict__ ptr, const int* __restrict__ part, int n)
{
    int i = blockIdx.x * 256 + threadIdx.x;
    if (i >= n) return;
    ptr[i] += part[blockIdx.x];
}

// ---------------- contention-free two-pass binning ----------------
__global__ __launch_bounds__(256) void histB(
    const int* __restrict__ dst, const int* __restrict__ attr, int* __restrict__ hist2)
{
    __shared__ int lh[NBUCK];
    int tid = threadIdx.x, blk = blockIdx.x;
    for (int i = tid; i < NBUCK; i += 256) lh[i] = 0;
    __syncthreads();
    int lo = blk * CHUNK, hi = lo + CHUNK; if (hi > NE) hi = NE;
    for (int e = lo + tid; e < hi; e += 256)
        atomicAdd(&lh[attr[e] * NRANGE + (dst[e] >> 8)], 1);
    __syncthreads();
    for (int i = tid; i < NBUCK; i += 256) hist2[i * BINB + blk] = lh[i];
}

__global__ __launch_bounds__(256) void binB(
    const int* __restrict__ src, const int* __restrict__ dst, const int* __restrict__ attr,
    const int* __restrict__ off2, uint* __restrict__ binned)
{
    __shared__ int lc[NBUCK];
    int tid = threadIdx.x, blk = blockIdx.x;
    for (int i = tid; i < NBUCK; i += 256) lc[i] = off2[i * BINB + blk];
    __syncthreads();
    int lo = blk * CHUNK, hi = lo + CHUNK; if (hi > NE) hi = NE;
    for (int e = lo + tid; e < hi; e += 256) {
        int d = dst[e];
        int b = attr[e] * NRANGE + (d >> 8);
        int pos = atomicAdd(&lc[b], 1);
        binned[pos] = (uint)src[e] | ((uint)(d & 255) << 16);   // src < 2^16
    }
}

// per-bucket: derive per-node CSR ptr (LDS hist+scan) and place edges into ssrc
__global__ __launch_bounds__(256) void bucket_finalize(
    const uint* __restrict__ binned, const int* __restrict__ off2,
    int* __restrict__ ptr, ushort* __restrict__ ssrc)
{
    __shared__ int lh[256];
    __shared__ int sc[256];
    __shared__ int cur[256];
    int b = blockIdx.x, tid = threadIdx.x;
    int rel = b / NRANGE, r0 = (b % NRANGE) << 8;
    int nloc = NN - r0; if (nloc > 256) nloc = 256;
    int lo = off2[b * BINB];
    int hi = (b + 1 < NBUCK) ? off2[(b + 1) * BINB] : NE;
    lh[tid] = 0;
    __syncthreads();
    for (int e = lo + tid; e < hi; e += 256)
        atomicAdd(&lh[(binned[e] >> 16) & 255], 1);
    __syncthreads();
    int v = lh[tid];
    sc[tid] = v;
    __syncthreads();
    #pragma unroll
    for (int off = 1; off < 256; off <<= 1) {
        int t = (tid >= off) ? sc[tid - off] : 0;
        __syncthreads();
        sc[tid] += t;
        __syncthreads();
    }
    int excl = lo + sc[tid] - v;
    if (tid < nloc) ptr[rel * NN + r0 + tid] = excl;
    cur[tid] = excl;
    if (b == NBUCK - 1 && tid == 0) ptr[3 * NN] = NE;
    __syncthreads();
    for (int e = lo + tid; e < hi; e += 256) {
        uint p = binned[e];
        int pos = atomicAdd(&cur[(p >> 16) & 255], 1);
        ssrc[pos] = (ushort)(p & 0xFFFFu);
    }
}

// ---------------- weight prep: Wt[m][n][k] = bf16(W[m][k][n]) ----------------
__global__ __launch_bounds__(256) void prep_w(
    const float* __restrict__ Ws_s, const float* __restrict__ Ws_k, ushort* __restrict__ wt)
{
    int i = blockIdx.x * 256 + threadIdx.x;
    if (i >= 9 * 4096) return;
    int m = i >> 12;
    int f = (i & 4095) * 4;
    int k = f >> 7, n = f & 127;
    const int tk[6] = {0, 3, 4, 6, 7, 8};
    const float* W = (m < 3) ? (Ws_s + (size_t)m * 16384)
                             : (Ws_k + (size_t)tk[m - 3] * 16384);
    float4 v = *(const float4*)(W + (size_t)k * DD + n);
    ushort* o = wt + (size_t)m * 16384 + k;
    o[(size_t)(n + 0) * DD] = f2b(v.x);
    o[(size_t)(n + 1) * DD] = f2b(v.y);
    o[(size_t)(n + 2) * DD] = f2b(v.z);
    o[(size_t)(n + 3) * DD] = f2b(v.w);
}

// ---------------- f32 -> bf16 convert ----------------
__global__ __launch_bounds__(256) void to_bf16(
    const float* __restrict__ x, ushort* __restrict__ xb)
{
    int i = blockIdx.x * 256 + threadIdx.x;
    if (i >= NN * DD / 4) return;
    float4 v = ((const float4*)x)[i];
    ushort4 o;
    o.x = f2b(v.x); o.y = f2b(v.y); o.z = f2b(v.z); o.w = f2b(v.w);
    ((ushort4*)xb)[i] = o;
}

// ---------------- batched gather from ONE table: blockIdx.y = rel -----------
// Single source table per dispatch -> small L2 working set (12.8 MB).
__global__ __launch_bounds__(256) void gather_multi(
    const ushort* __restrict__ h,
    const int* __restrict__ ptr, const ushort* __restrict__ ssrc,
    ushort* __restrict__ a0, ushort* __restrict__ a1, ushort* __restrict__ a2)
{
    int rel = blockIdx.y;
    ushort* agg = (rel == 0) ? a0 : ((rel == 1) ? a1 : a2);

    int n = blockIdx.x * 4 + (threadIdx.x >> 6);
    if (n >= NN) return;
    int lane = threadIdx.x & 63;
    const int* p = ptr + rel * NN + n;
    int s0 = __builtin_amdgcn_readfirstlane(p[0]);
    int s1 = __builtin_amdgcn_readfirstlane(p[1]);
    float a0f = 0.f, a1f = 0.f, c0f = 0.f, c1f = 0.f;
    int e = s0;
    for (; e + 8 <= s1; e += 8) {
        int idx[8];
        #pragma unroll
        for (int j = 0; j < 8; ++j) idx[j] = ssrc[e + j];
        uint v[8];
        #pragma unroll
        for (int j = 0; j < 8; ++j)
            v[j] = ((const uint*)(h + (size_t)idx[j] * DD))[lane];
        #pragma unroll
        for (int j = 0; j < 8; j += 2) {
            a0f += b2f((ushort)(v[j] & 0xFFFFu));     a1f += b2f((ushort)(v[j] >> 16));
            c0f += b2f((ushort)(v[j + 1] & 0xFFFFu)); c1f += b2f((ushort)(v[j + 1] >> 16));
        }
    }
    for (; e + 4 <= s1; e += 4) {
        int i0 = ssrc[e], i1 = ssrc[e + 1], i2 = ssrc[e + 2], i3 = ssrc[e + 3];
        uint v0 = ((const uint*)(h + (size_t)i0 * DD))[lane];
        uint v1 = ((const uint*)(h + (size_t)i1 * DD))[lane];
        uint v2 = ((const uint*)(h + (size_t)i2 * DD))[lane];
        uint v3 = ((const uint*)(h + (size_t)i3 * DD))[lane];
        a0f += b2f((ushort)(v0 & 0xFFFFu)); a1f += b2f((ushort)(v0 >> 16));
        c0f += b2f((ushort)(v1 & 0xFFFFu)); c1f += b2f((ushort)(v1 >> 16));
        a0f += b2f((ushort)(v2 & 0xFFFFu)); a1f += b2f((ushort)(v2 >> 16));
        c0f += b2f((ushort)(v3 & 0xFFFFu)); c1f += b2f((ushort)(v3 >> 16));
    }
    for (; e < s1; ++e) {
        int s = ssrc[e];
        uint v = ((const uint*)(h + (size_t)s * DD))[lane];
        a0f += b2f((ushort)(v & 0xFFFFu)); a1f += b2f((ushort)(v >> 16));
    }
    a0f += c0f; a1f += c1f;
    uint o = (uint)f2b(a0f) | ((uint)f2b(a1f) << 16);
    ((uint*)(agg + (size_t)n * DD))[lane] = o;
}

// ---------------- fused layer: x_new = x_old + sum_s relu(A_s @ W_s + b_s) ----
template<int NSRC, int WRITEB>
__global__ __launch_bounds__(256) void layer_mm(
    const ushort* __restrict__ s0, const ushort* __restrict__ s1,
    const ushort* __restrict__ s2, const ushort* __restrict__ s3,
    const ushort* __restrict__ w0, const ushort* __restrict__ w1,
    const ushort* __restrict__ w2, const ushort* __restrict__ w3,
    const float* __restrict__ b0, const float* __restrict__ b1,
    const float* __restrict__ b2, const float* __restrict__ b3,
    const float* __restrict__ xold, float* __restrict__ xnew, ushort* __restrict__ xbnew)
{
    __shared__ ushort Atile[64 * 128];   // XOR-swizzled
    const int tid  = threadIdx.x;
    const int wave = tid >> 6, lane = tid & 63;
    const int row0 = blockIdx.x * 64;

    const ushort* srcs[4] = { s0, s1, s2, s3 };
    const ushort* wts[4]  = { w0, w1, w2, w3 };
    const float*  bss[4]  = { b0, b1, b2, b3 };

    float facc[4][2][4];
    #pragma unroll
    for (int rt = 0; rt < 4; ++rt)
        #pragma unroll
        for (int ct = 0; ct < 2; ++ct)
            #pragma unroll
            for (int q = 0; q < 4; ++q) facc[rt][ct][q] = 0.f;

    #pragma unroll
    for (int sidx = 0; sidx < NSRC; ++sidx) {
        const ushort* S = srcs[sidx];
        const ushort* W = wts[sidx];

        __syncthreads();
        for (int i = tid; i < 1024; i += 256) {
            int r = i >> 4, c = i & 15;
            int gr = row0 + r;
            uint4 v = make_uint4(0, 0, 0, 0);
            if (gr < NN) v = ((const uint4*)(S + (size_t)gr * DD))[c];
            int byte = ((r << 8) + (c << 4)) ^ ((r & 7) << 4);
            *((uint4*)((char*)Atile + byte)) = v;
        }
        short8 bfr[2][4];
        #pragma unroll
        for (int ct = 0; ct < 2; ++ct)
            #pragma unroll
            for (int ks = 0; ks < 4; ++ks) {
                int col = (wave << 5) + (ct << 4) + (lane & 15);
                int kb  = (ks << 5) + ((lane >> 4) << 3);
                bfr[ct][ks] = *(const short8*)(W + (size_t)col * DD + kb);
            }
        __syncthreads();

        f32x4 c[4][2];
        #pragma unroll
        for (int rt = 0; rt < 4; ++rt)
            #pragma unroll
            for (int ct = 0; ct < 2; ++ct) c[rt][ct] = (f32x4)(0.f);

        #pragma unroll
        for (int rt = 0; rt < 4; ++rt) {
            int row = (rt << 4) + (lane & 15);
            #pragma unroll
            for (int ks = 0; ks < 4; ++ks) {
                int byte = ((row << 8) + (ks << 6) + ((lane >> 4) << 4)) ^ ((row & 7) << 4);
                short8 a = *((const short8*)((const char*)Atile + byte));
                c[rt][0] = __builtin_amdgcn_mfma_f32_16x16x32_bf16(a, bfr[0][ks], c[rt][0], 0, 0, 0);
                c[rt][1] = __builtin_amdgcn_mfma_f32_16x16x32_bf16(a, bfr[1][ks], c[rt][1], 0, 0, 0);
            }
        }

        const float* B = bss[sidx];
        #pragma unroll
        for (int ct = 0; ct < 2; ++ct) {
            float bb = B[(wave << 5) + (ct << 4) + (lane & 15)];
            #pragma unroll
            for (int rt = 0; rt < 4; ++rt)
                #pragma unroll
                for (int q = 0; q < 4; ++q) {
                    float v = c[rt][ct][q] + bb;
                    facc[rt][ct][q] += v > 0.f ? v : 0.f;
                }
        }
    }

    #pragma unroll
    for (int rt = 0; rt < 4; ++rt)
        #pragma unroll
        for (int q = 0; q < 4; ++q) {
            int row = row0 + (rt << 4) + ((lane >> 4) << 2) + q;
            if (row >= NN) continue;
            #pragma unroll
            for (int ct = 0; ct < 2; ++ct) {
                int col = (wave << 5) + (ct << 4) + (lane & 15);
                size_t off = (size_t)row * DD + col;
                float v = facc[rt][ct][q] + xold[off];
                xnew[off] = v;
                if (WRITEB) xbnew[off] = f2b(v);
            }
        }
}

extern "C" void kernel_launch(void* const* d_in, const int* in_sizes, int n_in,
                              void* d_out, int out_size, void* d_ws, size_t ws_size,
                              hipStream_t stream) {
    const float* x0   = (const float*)d_in[0];
    const float* Ws_s = (const float*)d_in[1];
    const float* bs_s = (const float*)d_in[2];
    const float* Ws_k = (const float*)d_in[3];
    const float* bs_k = (const float*)d_in[4];
    const int*   src  = (const int*)d_in[5];
    const int*   dst  = src + NE;
    const int*   attr = (const int*)d_in[6];
    float* out = (float*)d_out;

    // workspace carve-up (agg slots rotated: P0 serves A0->B0->C0)
    float*  x1   = (float*)d_ws;                         // 25.6 MB
    ushort* xb0  = (ushort*)(x1 + (size_t)NN * DD);      // 12.8 MB each
    ushort* xb1  = xb0 + (size_t)NN * DD;
    ushort* xb2  = xb1 + (size_t)NN * DD;
    ushort* P0   = xb2 + (size_t)NN * DD;                // aggA0 / aggB0 / aggC0
    ushort* P1   = P0 + (size_t)NN * DD;                 // aggA1 (hist2 alias pre-gather)
    ushort* P2   = P1 + (size_t)NN * DD;                 // aggB1 (off2 alias pre-gather)
    ushort* P3   = P2 + (size_t)NN * DD;                 // aggA2 (binned alias pre-gather)
    ushort* wtb  = P3 + (size_t)NN * DD;                 // 9 * 16384 * 2B
    int* ptr    = (int*)(wtb + 9 * 16384);               // 3N+1
    int* part2  = ptr + 3 * NN + 1;                      // 1024
    ushort* ssrc = (ushort*)(part2 + 1024);              // NE ushorts (3 MB)
    int* hist2  = (int*)P1;                              // NH2 ints (602 KB), dead after scan
    int* off2   = (int*)P2;                              // NH2 ints, dead after bucket_finalize
    uint* binned = (uint*)P3;                            // NE uints (6 MB), dead after bucket_finalize

    const int gGemm = (NN + 63) / 64;
    const int gGath = (NN + 3) / 4;
    const int gConv = (NN * DD / 4 + 255) / 256;
    const int NB2 = (NH2 + 255) / 256;      // 588

    auto wt = [&](int m) { return wtb + (size_t)m * 16384; };
    auto bk = [&](int t, int k) { return bs_k + ((size_t)t * 3 + k) * DD; };

    // ---------- binning + CSR (no global atomics) ----------
    histB<<<BINB, 256, 0, stream>>>(dst, attr, hist2);
    scan_block<<<NB2, 256, 0, stream>>>(hist2, off2, part2, NH2);
    scan_partials<<<1, 64, 0, stream>>>(part2, NB2);
    scan_add<<<NB2, 256, 0, stream>>>(off2, part2, NH2);
    binB<<<BINB, 256, 0, stream>>>(src, dst, attr, off2, binned);
    bucket_finalize<<<NBUCK, 256, 0, stream>>>(binned, off2, ptr, ssrc);
    // ---------- weight prep ----------
    prep_w<<<144, 256, 0, stream>>>(Ws_s, Ws_k, wtb);
    to_bf16<<<gConv, 256, 0, stream>>>(x0, xb0);

    // ---------- batch A: all gathers sourced from xb0 (rels 0,1,2) ----------
    gather_multi<<<dim3(gGath, 3), 256, 0, stream>>>(xb0, ptr, ssrc, P0, P1, P3);
    // ---------- layer 0 ----------
    layer_mm<2, 1><<<gGemm, 256, 0, stream>>>(
        xb0, P0, nullptr, nullptr,
        wt(0), wt(3), nullptr, nullptr,
        bs_s, bk(0, 0), nullptr, nullptr,
        x0, x1, xb1);

    // ---------- batch B: gathers sourced from xb1 (rels 0,1) ----------
    gather_multi<<<dim3(gGath, 2), 256, 0, stream>>>(xb1, ptr, ssrc, P0, P2, nullptr);
    // ---------- layer 1 ----------
    layer_mm<3, 1><<<gGemm, 256, 0, stream>>>(
        xb1, P0, P1, nullptr,
        wt(1), wt(4), wt(5), nullptr,
        bs_s + DD, bk(1, 0), bk(1, 1), nullptr,
        x1, out, xb2);                      // x2 lives in d_out

    // ---------- batch C: gather sourced from xb2 (rel 0) ----------
    gather_multi<<<dim3(gGath, 1), 256, 0, stream>>>(xb2, ptr, ssrc, P0, nullptr, nullptr);
    // ---------- layer 2 ----------
    layer_mm<4, 0><<<gGemm, 256, 0, stream>>>(
        xb2, P0, P2, P3,
        wt(2), wt(6), wt(7), wt(8),
        bs_s + 2 * DD, bk(2, 0), bk(2, 1), bk(2, 2),
        out, out, nullptr);                 // x3 overwrites x2 in d_out
}

// Round 9
// 295.216 us; speedup vs baseline: 1.0112x; 1.0112x over previous
//
#include <hip/hip_runtime.h>

#define NN 50000
#define NE 1500000
#define DD 128
#define NRANGE ((NN + 255) / 256)      // 196 dst-ranges of 256 nodes
#define NBUCK (3 * NRANGE)             // 588 (rel, range) buckets
#define BINB 256                       // binning blocks
#define CHUNK ((NE + BINB - 1) / BINB) // 5860 edges per binning block
#define NH2 (NBUCK * BINB)             // 150528 hist2 entries
#define GCONV ((NN * DD / 4 + 255) / 256)  // 6250 to_bf16 blocks

typedef __attribute__((ext_vector_type(8))) short short8;
typedef __attribute__((ext_vector_type(4))) float f32x4;

__device__ __forceinline__ ushort f2b(float x) {
    uint u = __float_as_uint(x);
    u += 0x7FFFu + ((u >> 16) & 1u);
    return (ushort)(u >> 16);
}
__device__ __forceinline__ float b2f(ushort b) {
    return __uint_as_float(((uint)b) << 16);
}

// ---------------- scan helpers ----------------
__global__ __launch_bounds__(256) void scan_block(
    const int* __restrict__ cnt, int* __restrict__ ptr, int* __restrict__ part, int n)
{
    __shared__ int s[256];
    int i = blockIdx.x * 256 + threadIdx.x;
    int v = (i < n) ? cnt[i] : 0;
    s[threadIdx.x] = v;
    __syncthreads();
    #pragma unroll
    for (int off = 1; off < 256; off <<= 1) {
        int t = (threadIdx.x >= off) ? s[threadIdx.x - off] : 0;
        __syncthreads();
        s[threadIdx.x] += t;
        __syncthreads();
    }
    if (i < n) ptr[i] = s[threadIdx.x] - v;
    if (threadIdx.x == 255) part[blockIdx.x] = s[255];
}

__global__ void scan_partials(int* __restrict__ part, int nb)
{
    int lane = threadIdx.x;
    int run = 0;
    for (int base = 0; base < nb; base += 64) {
        int i = base + lane;
        int v = (i < nb) ? part[i] : 0;
        int x = v;
        #pragma unroll
        for (int off = 1; off < 64; off <<= 1) {
            int t = __shfl_up(x, off);
            if (lane >= off) x += t;
        }
        if (i < nb) part[i] = run + x - v;
        run += __shfl(x, 63);
    }
}

__global__ __launch_bounds__(256) void scan_add(
    int* __restrict__ ptr, const int* __restrict__ part, int n)
{
    int i = blockIdx.x * 256 + threadIdx.x;
    if (i >= n) return;
    ptr[i] += part[blockIdx.x];
}

// ---------------- fused prologue: histB | to_bf16 | prep_w ----------------
__global__ __launch_bounds__(256) void prep_all(
    const int* __restrict__ dst, const int* __restrict__ attr, int* __restrict__ hist2,
    const float* __restrict__ x, ushort* __restrict__ xb,
    const float* __restrict__ Ws_s, const float* __restrict__ Ws_k, ushort* __restrict__ wt)
{
    __shared__ int lh[NBUCK];
    int b = blockIdx.x, tid = threadIdx.x;
    if (b < BINB) {
        // per-block LDS histogram over (rel, dst/256) buckets
        for (int i = tid; i < NBUCK; i += 256) lh[i] = 0;
        __syncthreads();
        int lo = b * CHUNK, hi = lo + CHUNK; if (hi > NE) hi = NE;
        for (int e = lo + tid; e < hi; e += 256)
            atomicAdd(&lh[attr[e] * NRANGE + (dst[e] >> 8)], 1);
        __syncthreads();
        for (int i = tid; i < NBUCK; i += 256) hist2[i * BINB + b] = lh[i];
    } else if (b < BINB + GCONV) {
        int i = (b - BINB) * 256 + tid;
        if (i < NN * DD / 4) {
            float4 v = ((const float4*)x)[i];
            ushort4 o;
            o.x = f2b(v.x); o.y = f2b(v.y); o.z = f2b(v.z); o.w = f2b(v.w);
            ((ushort4*)xb)[i] = o;
        }
    } else {
        int i = (b - BINB - GCONV) * 256 + tid;
        if (i < 9 * 4096) {
            int m = i >> 12;
            int f = (i & 4095) * 4;
            int k = f >> 7, n = f & 127;
            const int tk[6] = {0, 3, 4, 6, 7, 8};
            const float* W = (m < 3) ? (Ws_s + (size_t)m * 16384)
                                     : (Ws_k + (size_t)tk[m - 3] * 16384);
            float4 v = *(const float4*)(W + (size_t)k * DD + n);
            ushort* o = wt + (size_t)m * 16384 + k;
            o[(size_t)(n + 0) * DD] = f2b(v.x);
            o[(size_t)(n + 1) * DD] = f2b(v.y);
            o[(size_t)(n + 2) * DD] = f2b(v.z);
            o[(size_t)(n + 3) * DD] = f2b(v.w);
        }
    }
}

// ---------------- contention-free binning ----------------
__global__ __launch_bounds__(256) void binB(
    const int* __restrict__ src, const int* __restrict__ dst, const int* __restrict__ attr,
    const int* __restrict__ off2, uint* __restrict__ binned)
{
    __shared__ int lc[NBUCK];
    int tid = threadIdx.x, blk = blockIdx.x;
    for (int i = tid; i < NBUCK; i += 256) lc[i] = off2[i * BINB + blk];
    __syncthreads();
    int lo = blk * CHUNK, hi = lo + CHUNK; if (hi > NE) hi = NE;
    for (int e = lo + tid; e < hi; e += 256) {
        int d = dst[e];
        int b = attr[e] * NRANGE + (d >> 8);
        int pos = atomicAdd(&lc[b], 1);
        binned[pos] = (uint)src[e] | ((uint)(d & 255) << 16);   // src < 2^16
    }
}

// per-bucket: derive per-node CSR ptr (LDS hist+scan) and place edges into ssrc
__global__ __launch_bounds__(256) void bucket_finalize(
    const uint* __restrict__ binned, const int* __restrict__ off2,
    int* __restrict__ ptr, ushort* __restrict__ ssrc)
{
    __shared__ int lh[256];
    __shared__ int sc[256];
    __shared__ int cur[256];
    int b = blockIdx.x, tid = threadIdx.x;
    int rel = b / NRANGE, r0 = (b % NRANGE) << 8;
    int nloc = NN - r0; if (nloc > 256) nloc = 256;
    int lo = off2[b * BINB];
    int hi = (b + 1 < NBUCK) ? off2[(b + 1) * BINB] : NE;
    lh[tid] = 0;
    __syncthreads();
    for (int e = lo + tid; e < hi; e += 256)
        atomicAdd(&lh[(binned[e] >> 16) & 255], 1);
    __syncthreads();
    int v = lh[tid];
    sc[tid] = v;
    __syncthreads();
    #pragma unroll
    for (int off = 1; off < 256; off <<= 1) {
        int t = (tid >= off) ? sc[tid - off] : 0;
        __syncthreads();
        sc[tid] += t;
        __syncthreads();
    }
    int excl = lo + sc[tid] - v;
    if (tid < nloc) ptr[rel * NN + r0 + tid] = excl;
    cur[tid] = excl;
    if (b == NBUCK - 1 && tid == 0) ptr[3 * NN] = NE;
    __syncthreads();
    for (int e = lo + tid; e < hi; e += 256) {
        uint p = binned[e];
        int pos = atomicAdd(&cur[(p >> 16) & 255], 1);
        ssrc[pos] = (ushort)(p & 0xFFFFu);
    }
}

// ---------------- layer-grouped gather: blockIdx.y = rel, per-rel table -----
__global__ __launch_bounds__(256) void gather_multi(
    const ushort* __restrict__ h0, const ushort* __restrict__ h1,
    const ushort* __restrict__ h2,
    const int* __restrict__ ptr, const ushort* __restrict__ ssrc,
    ushort* __restrict__ a0, ushort* __restrict__ a1, ushort* __restrict__ a2)
{
    int rel = blockIdx.y;
    const ushort* h = (rel == 0) ? h0 : ((rel == 1) ? h1 : h2);
    ushort* agg     = (rel == 0) ? a0 : ((rel == 1) ? a1 : a2);

    int n = blockIdx.x * 4 + (threadIdx.x >> 6);
    if (n >= NN) return;
    int lane = threadIdx.x & 63;
    const int* p = ptr + rel * NN + n;
    int s0 = __builtin_amdgcn_readfirstlane(p[0]);
    int s1 = __builtin_amdgcn_readfirstlane(p[1]);
    float A0 = 0.f, A1 = 0.f, C0 = 0.f, C1 = 0.f;
    int e = s0;
    // software-pipelined main loop: prefetch next 8 idx under current 8 row loads
    int idx[8];
    bool have = (e + 8 <= s1);
    if (have) {
        #pragma unroll
        for (int j = 0; j < 8; ++j) idx[j] = ssrc[e + j];
    }
    while (have) {
        uint v[8];
        #pragma unroll
        for (int j = 0; j < 8; ++j)
            v[j] = ((const uint*)(h + (size_t)idx[j] * DD))[lane];
        int e2 = e + 8;
        bool nxt = (e2 + 8 <= s1);
        if (nxt) {
            #pragma unroll
            for (int j = 0; j < 8; ++j) idx[j] = ssrc[e2 + j];
        }
        #pragma unroll
        for (int j = 0; j < 8; j += 2) {
            A0 += b2f((ushort)(v[j] & 0xFFFFu));     A1 += b2f((ushort)(v[j] >> 16));
            C0 += b2f((ushort)(v[j + 1] & 0xFFFFu)); C1 += b2f((ushort)(v[j + 1] >> 16));
        }
        e = e2; have = nxt;
    }
    for (; e + 4 <= s1; e += 4) {
        int i0 = ssrc[e], i1 = ssrc[e + 1], i2 = ssrc[e + 2], i3 = ssrc[e + 3];
        uint v0 = ((const uint*)(h + (size_t)i0 * DD))[lane];
        uint v1 = ((const uint*)(h + (size_t)i1 * DD))[lane];
        uint v2 = ((const uint*)(h + (size_t)i2 * DD))[lane];
        uint v3 = ((const uint*)(h + (size_t)i3 * DD))[lane];
        A0 += b2f((ushort)(v0 & 0xFFFFu)); A1 += b2f((ushort)(v0 >> 16));
        C0 += b2f((ushort)(v1 & 0xFFFFu)); C1 += b2f((ushort)(v1 >> 16));
        A0 += b2f((ushort)(v2 & 0xFFFFu)); A1 += b2f((ushort)(v2 >> 16));
        C0 += b2f((ushort)(v3 & 0xFFFFu)); C1 += b2f((ushort)(v3 >> 16));
    }
    for (; e < s1; ++e) {
        int s = ssrc[e];
        uint v = ((const uint*)(h + (size_t)s * DD))[lane];
        A0 += b2f((ushort)(v & 0xFFFFu)); A1 += b2f((ushort)(v >> 16));
    }
    A0 += C0; A1 += C1;
    uint o = (uint)f2b(A0) | ((uint)f2b(A1) << 16);
    ((uint*)(agg + (size_t)n * DD))[lane] = o;
}

// ---------------- fused layer: x_new = x_old + sum_s relu(A_s @ W_s + b_s) ----
template<int NSRC, int WRITEB>
__global__ __launch_bounds__(256) void layer_mm(
    const ushort* __restrict__ s0, const ushort* __restrict__ s1,
    const ushort* __restrict__ s2, const ushort* __restrict__ s3,
    const ushort* __restrict__ w0, const ushort* __restrict__ w1,
    const ushort* __restrict__ w2, const ushort* __restrict__ w3,
    const float* __restrict__ b0, const float* __restrict__ b1,
    const float* __restrict__ b2, const float* __restrict__ b3,
    const float* __restrict__ xold, float* __restrict__ xnew, ushort* __restrict__ xbnew)
{
    __shared__ ushort Atile[64 * 128];   // XOR-swizzled
    const int tid  = threadIdx.x;
    const int wave = tid >> 6, lane = tid & 63;
    const int row0 = blockIdx.x * 64;

    const ushort* srcs[4] = { s0, s1, s2, s3 };
    const ushort* wts[4]  = { w0, w1, w2, w3 };
    const float*  bss[4]  = { b0, b1, b2, b3 };

    float facc[4][2][4];
    #pragma unroll
    for (int rt = 0; rt < 4; ++rt)
        #pragma unroll
        for (int ct = 0; ct < 2; ++ct)
            #pragma unroll
            for (int q = 0; q < 4; ++q) facc[rt][ct][q] = 0.f;

    #pragma unroll
    for (int sidx = 0; sidx < NSRC; ++sidx) {
        const ushort* S = srcs[sidx];
        const ushort* W = wts[sidx];

        __syncthreads();
        for (int i = tid; i < 1024; i += 256) {
            int r = i >> 4, c = i & 15;
            int gr = row0 + r;
            uint4 v = make_uint4(0, 0, 0, 0);
            if (gr < NN) v = ((const uint4*)(S + (size_t)gr * DD))[c];
            int byte = ((r << 8) + (c << 4)) ^ ((r & 7) << 4);
            *((uint4*)((char*)Atile + byte)) = v;
        }
        short8 bfr[2][4];
        #pragma unroll
        for (int ct = 0; ct < 2; ++ct)
            #pragma unroll
            for (int ks = 0; ks < 4; ++ks) {
                int col = (wave << 5) + (ct << 4) + (lane & 15);
                int kb  = (ks << 5) + ((lane >> 4) << 3);
                bfr[ct][ks] = *(const short8*)(W + (size_t)col * DD + kb);
            }
        __syncthreads();

        f32x4 c[4][2];
        #pragma unroll
        for (int rt = 0; rt < 4; ++rt)
            #pragma unroll
            for (int ct = 0; ct < 2; ++ct) c[rt][ct] = (f32x4)(0.f);

        #pragma unroll
        for (int rt = 0; rt < 4; ++rt) {
            int row = (rt << 4) + (lane & 15);
            #pragma unroll
            for (int ks = 0; ks < 4; ++ks) {
                int byte = ((row << 8) + (ks << 6) + ((lane >> 4) << 4)) ^ ((row & 7) << 4);
                short8 a = *((const short8*)((const char*)Atile + byte));
                c[rt][0] = __builtin_amdgcn_mfma_f32_16x16x32_bf16(a, bfr[0][ks], c[rt][0], 0, 0, 0);
                c[rt][1] = __builtin_amdgcn_mfma_f32_16x16x32_bf16(a, bfr[1][ks], c[rt][1], 0, 0, 0);
            }
        }

        const float* B = bss[sidx];
        #pragma unroll
        for (int ct = 0; ct < 2; ++ct) {
            float bb = B[(wave << 5) + (ct << 4) + (lane & 15)];
            #pragma unroll
            for (int rt = 0; rt < 4; ++rt)
                #pragma unroll
                for (int q = 0; q < 4; ++q) {
                    float v = c[rt][ct][q] + bb;
                    facc[rt][ct][q] += v > 0.f ? v : 0.f;
                }
        }
    }

    #pragma unroll
    for (int rt = 0; rt < 4; ++rt)
        #pragma unroll
        for (int q = 0; q < 4; ++q) {
            int row = row0 + (rt << 4) + ((lane >> 4) << 2) + q;
            if (row >= NN) continue;
            #pragma unroll
            for (int ct = 0; ct < 2; ++ct) {
                int col = (wave << 5) + (ct << 4) + (lane & 15);
                size_t off = (size_t)row * DD + col;
                float v = facc[rt][ct][q] + xold[off];
                xnew[off] = v;
                if (WRITEB) xbnew[off] = f2b(v);
            }
        }
}

extern "C" void kernel_launch(void* const* d_in, const int* in_sizes, int n_in,
                              void* d_out, int out_size, void* d_ws, size_t ws_size,
                              hipStream_t stream) {
    const float* x0   = (const float*)d_in[0];
    const float* Ws_s = (const float*)d_in[1];
    const float* bs_s = (const float*)d_in[2];
    const float* Ws_k = (const float*)d_in[3];
    const float* bs_k = (const float*)d_in[4];
    const int*   src  = (const int*)d_in[5];
    const int*   dst  = src + NE;
    const int*   attr = (const int*)d_in[6];
    float* out = (float*)d_out;

    // workspace carve-up
    float*  x1   = (float*)d_ws;                         // 25.6 MB
    ushort* xb0  = (ushort*)(x1 + (size_t)NN * DD);      // 12.8 MB each
    ushort* xb1  = xb0 + (size_t)NN * DD;
    ushort* xb2  = xb1 + (size_t)NN * DD;
    ushort* P0   = xb2 + (size_t)NN * DD;                // agg slot (binned alias pre-gather)
    ushort* P1   = P0 + (size_t)NN * DD;                 // agg slot (hist2+off2 alias pre-gather)
    ushort* P2   = P1 + (size_t)NN * DD;                 // agg slot
    ushort* wtb  = P2 + (size_t)NN * DD;                 // 9 * 16384 * 2B
    int* ptr    = (int*)(wtb + 9 * 16384);               // 3N+1
    int* part2  = ptr + 3 * NN + 1;                      // 1024
    ushort* ssrc = (ushort*)(part2 + 1024);              // NE ushorts (3 MB)
    uint* binned = (uint*)P0;                            // NE uints (6 MB), dead after finalize
    int* hist2  = (int*)P1;                              // NH2 ints (602 KB), dead after scan
    int* off2   = hist2 + NH2;                           // NH2 ints, dead after finalize

    const int gGemm = (NN + 63) / 64;
    const int gGath = (NN + 3) / 4;
    const int NB2 = (NH2 + 255) / 256;      // 588

    auto wt = [&](int m) { return wtb + (size_t)m * 16384; };
    auto bk = [&](int t, int k) { return bs_k + ((size_t)t * 3 + k) * DD; };

    // ---------- fused prologue + binning + CSR (no global atomics) ----------
    prep_all<<<BINB + GCONV + 144, 256, 0, stream>>>(
        dst, attr, hist2, x0, xb0, Ws_s, Ws_k, wtb);
    scan_block<<<NB2, 256, 0, stream>>>(hist2, off2, part2, NH2);
    scan_partials<<<1, 64, 0, stream>>>(part2, NB2);
    scan_add<<<NB2, 256, 0, stream>>>(off2, part2, NH2);
    binB<<<BINB, 256, 0, stream>>>(src, dst, attr, off2, binned);
    bucket_finalize<<<NBUCK, 256, 0, stream>>>(binned, off2, ptr, ssrc);

    // ---------- layer 0 ----------
    gather_multi<<<dim3(gGath, 1), 256, 0, stream>>>(
        xb0, nullptr, nullptr, ptr, ssrc, P0, nullptr, nullptr);
    layer_mm<2, 1><<<gGemm, 256, 0, stream>>>(
        xb0, P0, nullptr, nullptr,
        wt(0), wt(3), nullptr, nullptr,
        bs_s, bk(0, 0), nullptr, nullptr,
        x0, x1, xb1);

    // ---------- layer 1 ----------
    gather_multi<<<dim3(gGath, 2), 256, 0, stream>>>(
        xb1, xb0, nullptr, ptr, ssrc, P0, P1, nullptr);
    layer_mm<3, 1><<<gGemm, 256, 0, stream>>>(
        xb1, P0, P1, nullptr,
        wt(1), wt(4), wt(5), nullptr,
        bs_s + DD, bk(1, 0), bk(1, 1), nullptr,
        x1, out, xb2);                      // x2 lives in d_out

    // ---------- layer 2 ----------
    gather_multi<<<dim3(gGath, 3), 256, 0, stream>>>(
        xb2, xb1, xb0, ptr, ssrc, P0, P1, P2);
    layer_mm<4, 0><<<gGemm, 256, 0, stream>>>(
        xb2, P0, P1, P2,
        wt(2), wt(6), wt(7), wt(8),
        bs_s + 2 * DD, bk(2, 0), bk(2, 1), bk(2, 2),
        out, out, nullptr);                 // x3 overwrites x2 in d_out
}

// Round 10
// 276.073 us; speedup vs baseline: 1.0813x; 1.0693x over previous
//
#include <hip/hip_runtime.h>

#define NN 50000
#define NE 1500000
#define DD 128
#define NRANGE ((NN + 255) / 256)      // 196 dst-ranges of 256 nodes
#define NBUCK (3 * NRANGE)             // 588 (rel, range) buckets
#define BINB 256                       // binning blocks
#define CHUNK ((NE + BINB - 1) / BINB) // 5860 edges per binning block
#define NH2 (NBUCK * BINB)             // 150528 hist2 entries
#define GCONV ((NN * DD / 4 + 255) / 256)  // 6250 to_bf16 blocks

typedef __attribute__((ext_vector_type(8))) short short8;
typedef __attribute__((ext_vector_type(4))) float f32x4;

__device__ __forceinline__ ushort f2b(float x) {
    uint u = __float_as_uint(x);
    u += 0x7FFFu + ((u >> 16) & 1u);
    return (ushort)(u >> 16);
}
__device__ __forceinline__ float b2f(ushort b) {
    return __uint_as_float(((uint)b) << 16);
}

// ---------------- scan helpers ----------------
__global__ __launch_bounds__(256) void scan_block(
    const int* __restrict__ cnt, int* __restrict__ ptr, int* __restrict__ part, int n)
{
    __shared__ int s[256];
    int i = blockIdx.x * 256 + threadIdx.x;
    int v = (i < n) ? cnt[i] : 0;
    s[threadIdx.x] = v;
    __syncthreads();
    #pragma unroll
    for (int off = 1; off < 256; off <<= 1) {
        int t = (threadIdx.x >= off) ? s[threadIdx.x - off] : 0;
        __syncthreads();
        s[threadIdx.x] += t;
        __syncthreads();
    }
    if (i < n) ptr[i] = s[threadIdx.x] - v;
    if (threadIdx.x == 255) part[blockIdx.x] = s[255];
}

__global__ void scan_partials(int* __restrict__ part, int nb)
{
    int lane = threadIdx.x;
    int run = 0;
    for (int base = 0; base < nb; base += 64) {
        int i = base + lane;
        int v = (i < nb) ? part[i] : 0;
        int x = v;
        #pragma unroll
        for (int off = 1; off < 64; off <<= 1) {
            int t = __shfl_up(x, off);
            if (lane >= off) x += t;
        }
        if (i < nb) part[i] = run + x - v;
        run += __shfl(x, 63);
    }
}

__global__ __launch_bounds__(256) void scan_add(
    int* __restrict__ ptr, const int* __restrict__ part, int n)
{
    int i = blockIdx.x * 256 + threadIdx.x;
    if (i >= n) return;
    ptr[i] += part[blockIdx.x];
}

// ---------------- fused prologue: histB | to_bf16 | prep_w ----------------
__global__ __launch_bounds__(256) void prep_all(
    const int* __restrict__ dst, const int* __restrict__ attr, int* __restrict__ hist2,
    const float* __restrict__ x, ushort* __restrict__ xb,
    const float* __restrict__ Ws_s, const float* __restrict__ Ws_k, ushort* __restrict__ wt)
{
    __shared__ int lh[NBUCK];
    int b = blockIdx.x, tid = threadIdx.x;
    if (b < BINB) {
        for (int i = tid; i < NBUCK; i += 256) lh[i] = 0;
        __syncthreads();
        int lo = b * CHUNK, hi = lo + CHUNK; if (hi > NE) hi = NE;
        for (int e = lo + tid; e < hi; e += 256)
            atomicAdd(&lh[attr[e] * NRANGE + (dst[e] >> 8)], 1);
        __syncthreads();
        for (int i = tid; i < NBUCK; i += 256) hist2[i * BINB + b] = lh[i];
    } else if (b < BINB + GCONV) {
        int i = (b - BINB) * 256 + tid;
        if (i < NN * DD / 4) {
            float4 v = ((const float4*)x)[i];
            ushort4 o;
            o.x = f2b(v.x); o.y = f2b(v.y); o.z = f2b(v.z); o.w = f2b(v.w);
            ((ushort4*)xb)[i] = o;
        }
    } else {
        int i = (b - BINB - GCONV) * 256 + tid;
        if (i < 9 * 4096) {
            int m = i >> 12;
            int f = (i & 4095) * 4;
            int k = f >> 7, n = f & 127;
            const int tk[6] = {0, 3, 4, 6, 7, 8};
            const float* W = (m < 3) ? (Ws_s + (size_t)m * 16384)
                                     : (Ws_k + (size_t)tk[m - 3] * 16384);
            float4 v = *(const float4*)(W + (size_t)k * DD + n);
            ushort* o = wt + (size_t)m * 16384 + k;
            o[(size_t)(n + 0) * DD] = f2b(v.x);
            o[(size_t)(n + 1) * DD] = f2b(v.y);
            o[(size_t)(n + 2) * DD] = f2b(v.z);
            o[(size_t)(n + 3) * DD] = f2b(v.w);
        }
    }
}

// ---------------- contention-free binning ----------------
__global__ __launch_bounds__(256) void binB(
    const int* __restrict__ src, const int* __restrict__ dst, const int* __restrict__ attr,
    const int* __restrict__ off2, uint* __restrict__ binned)
{
    __shared__ int lc[NBUCK];
    int tid = threadIdx.x, blk = blockIdx.x;
    for (int i = tid; i < NBUCK; i += 256) lc[i] = off2[i * BINB + blk];
    __syncthreads();
    int lo = blk * CHUNK, hi = lo + CHUNK; if (hi > NE) hi = NE;
    for (int e = lo + tid; e < hi; e += 256) {
        int d = dst[e];
        int b = attr[e] * NRANGE + (d >> 8);
        int pos = atomicAdd(&lc[b], 1);
        binned[pos] = (uint)src[e] | ((uint)(d & 255) << 16);   // src < 2^16
    }
}

// per-bucket: derive per-node CSR ptr (LDS hist+scan) and place edges into ssrc
__global__ __launch_bounds__(256) void bucket_finalize(
    const uint* __restrict__ binned, const int* __restrict__ off2,
    int* __restrict__ ptr, int* __restrict__ ssrc)
{
    __shared__ int lh[256];
    __shared__ int sc[256];
    __shared__ int cur[256];
    int b = blockIdx.x, tid = threadIdx.x;
    int rel = b / NRANGE, r0 = (b % NRANGE) << 8;
    int nloc = NN - r0; if (nloc > 256) nloc = 256;
    int lo = off2[b * BINB];
    int hi = (b + 1 < NBUCK) ? off2[(b + 1) * BINB] : NE;
    lh[tid] = 0;
    __syncthreads();
    for (int e = lo + tid; e < hi; e += 256)
        atomicAdd(&lh[(binned[e] >> 16) & 255], 1);
    __syncthreads();
    int v = lh[tid];
    sc[tid] = v;
    __syncthreads();
    #pragma unroll
    for (int off = 1; off < 256; off <<= 1) {
        int t = (tid >= off) ? sc[tid - off] : 0;
        __syncthreads();
        sc[tid] += t;
        __syncthreads();
    }
    int excl = lo + sc[tid] - v;
    if (tid < nloc) ptr[rel * NN + r0 + tid] = excl;
    cur[tid] = excl;
    if (b == NBUCK - 1 && tid == 0) ptr[3 * NN] = NE;
    __syncthreads();
    for (int e = lo + tid; e < hi; e += 256) {
        uint p = binned[e];
        int pos = atomicAdd(&cur[(p >> 16) & 255], 1);
        ssrc[pos] = (int)(p & 0xFFFFu);
    }
}

// ---------------- layer-grouped gather, 2 nodes per wave -------------------
// Half-wave (32 lanes) per node; each lane covers 4 bf16 via uint2.
// Every VMEM row-load instruction fetches TWO independent rows -> 2x MLP.
__global__ __launch_bounds__(256) void gather_multi(
    const ushort* __restrict__ h0, const ushort* __restrict__ h1,
    const ushort* __restrict__ h2,
    const int* __restrict__ ptr, const int* __restrict__ ssrc,
    ushort* __restrict__ a0, ushort* __restrict__ a1, ushort* __restrict__ a2)
{
    int rel = blockIdx.y;
    const ushort* h = (rel == 0) ? h0 : ((rel == 1) ? h1 : h2);
    ushort* agg     = (rel == 0) ? a0 : ((rel == 1) ? a1 : a2);

    int tid  = threadIdx.x;
    int half = (tid >> 5) & 1;
    int sub  = tid & 31;
    int n = blockIdx.x * 8 + ((tid >> 6) << 1) + half;
    if (n >= NN) return;
    const int* p = ptr + rel * NN + n;
    int s0 = p[0], s1 = p[1];          // broadcast within half-wave
    float A0 = 0.f, A1 = 0.f, A2 = 0.f, A3 = 0.f;
    int e = s0;
    for (; e + 8 <= s1; e += 8) {
        int idx[8];
        #pragma unroll
        for (int j = 0; j < 8; ++j) idx[j] = ssrc[e + j];
        uint2 v[8];
        #pragma unroll
        for (int j = 0; j < 8; ++j)
            v[j] = ((const uint2*)(h + (size_t)idx[j] * DD))[sub];
        #pragma unroll
        for (int j = 0; j < 8; ++j) {
            A0 += b2f((ushort)(v[j].x & 0xFFFFu)); A1 += b2f((ushort)(v[j].x >> 16));
            A2 += b2f((ushort)(v[j].y & 0xFFFFu)); A3 += b2f((ushort)(v[j].y >> 16));
        }
    }
    if (e + 4 <= s1) {
        int i0 = ssrc[e], i1 = ssrc[e + 1], i2 = ssrc[e + 2], i3 = ssrc[e + 3];
        uint2 v0 = ((const uint2*)(h + (size_t)i0 * DD))[sub];
        uint2 v1 = ((const uint2*)(h + (size_t)i1 * DD))[sub];
        uint2 v2 = ((const uint2*)(h + (size_t)i2 * DD))[sub];
        uint2 v3 = ((const uint2*)(h + (size_t)i3 * DD))[sub];
        A0 += b2f((ushort)(v0.x & 0xFFFFu)); A1 += b2f((ushort)(v0.x >> 16));
        A2 += b2f((ushort)(v0.y & 0xFFFFu)); A3 += b2f((ushort)(v0.y >> 16));
        A0 += b2f((ushort)(v1.x & 0xFFFFu)); A1 += b2f((ushort)(v1.x >> 16));
        A2 += b2f((ushort)(v1.y & 0xFFFFu)); A3 += b2f((ushort)(v1.y >> 16));
        A0 += b2f((ushort)(v2.x & 0xFFFFu)); A1 += b2f((ushort)(v2.x >> 16));
        A2 += b2f((ushort)(v2.y & 0xFFFFu)); A3 += b2f((ushort)(v2.y >> 16));
        A0 += b2f((ushort)(v3.x & 0xFFFFu)); A1 += b2f((ushort)(v3.x >> 16));
        A2 += b2f((ushort)(v3.y & 0xFFFFu)); A3 += b2f((ushort)(v3.y >> 16));
        e += 4;
    }
    for (; e < s1; ++e) {
        int s = ssrc[e];
        uint2 v = ((const uint2*)(h + (size_t)s * DD))[sub];
        A0 += b2f((ushort)(v.x & 0xFFFFu)); A1 += b2f((ushort)(v.x >> 16));
        A2 += b2f((ushort)(v.y & 0xFFFFu)); A3 += b2f((ushort)(v.y >> 16));
    }
    uint2 o;
    o.x = (uint)f2b(A0) | ((uint)f2b(A1) << 16);
    o.y = (uint)f2b(A2) | ((uint)f2b(A3) << 16);
    ((uint2*)(agg + (size_t)n * DD))[sub] = o;
}

// ---------------- fused layer: x_new = x_old + sum_s relu(A_s @ W_s + b_s) ----
template<int NSRC, int WRITEB>
__global__ __launch_bounds__(256) void layer_mm(
    const ushort* __restrict__ s0, const ushort* __restrict__ s1,
    const ushort* __restrict__ s2, const ushort* __restrict__ s3,
    const ushort* __restrict__ w0, const ushort* __restrict__ w1,
    const ushort* __restrict__ w2, const ushort* __restrict__ w3,
    const float* __restrict__ b0, const float* __restrict__ b1,
    const float* __restrict__ b2, const float* __restrict__ b3,
    const float* __restrict__ xold, float* __restrict__ xnew, ushort* __restrict__ xbnew)
{
    __shared__ ushort Atile[64 * 128];   // XOR-swizzled
    const int tid  = threadIdx.x;
    const int wave = tid >> 6, lane = tid & 63;
    const int row0 = blockIdx.x * 64;

    const ushort* srcs[4] = { s0, s1, s2, s3 };
    const ushort* wts[4]  = { w0, w1, w2, w3 };
    const float*  bss[4]  = { b0, b1, b2, b3 };

    float facc[4][2][4];
    #pragma unroll
    for (int rt = 0; rt < 4; ++rt)
        #pragma unroll
        for (int ct = 0; ct < 2; ++ct)
            #pragma unroll
            for (int q = 0; q < 4; ++q) facc[rt][ct][q] = 0.f;

    #pragma unroll
    for (int sidx = 0; sidx < NSRC; ++sidx) {
        const ushort* S = srcs[sidx];
        const ushort* W = wts[sidx];

        __syncthreads();
        for (int i = tid; i < 1024; i += 256) {
            int r = i >> 4, c = i & 15;
            int gr = row0 + r;
            uint4 v = make_uint4(0, 0, 0, 0);
            if (gr < NN) v = ((const uint4*)(S + (size_t)gr * DD))[c];
            int byte = ((r << 8) + (c << 4)) ^ ((r & 7) << 4);
            *((uint4*)((char*)Atile + byte)) = v;
        }
        short8 bfr[2][4];
        #pragma unroll
        for (int ct = 0; ct < 2; ++ct)
            #pragma unroll
            for (int ks = 0; ks < 4; ++ks) {
                int col = (wave << 5) + (ct << 4) + (lane & 15);
                int kb  = (ks << 5) + ((lane >> 4) << 3);
                bfr[ct][ks] = *(const short8*)(W + (size_t)col * DD + kb);
            }
        __syncthreads();

        f32x4 c[4][2];
        #pragma unroll
        for (int rt = 0; rt < 4; ++rt)
            #pragma unroll
            for (int ct = 0; ct < 2; ++ct) c[rt][ct] = (f32x4)(0.f);

        #pragma unroll
        for (int rt = 0; rt < 4; ++rt) {
            int row = (rt << 4) + (lane & 15);
            #pragma unroll
            for (int ks = 0; ks < 4; ++ks) {
                int byte = ((row << 8) + (ks << 6) + ((lane >> 4) << 4)) ^ ((row & 7) << 4);
                short8 a = *((const short8*)((const char*)Atile + byte));
                c[rt][0] = __builtin_amdgcn_mfma_f32_16x16x32_bf16(a, bfr[0][ks], c[rt][0], 0, 0, 0);
                c[rt][1] = __builtin_amdgcn_mfma_f32_16x16x32_bf16(a, bfr[1][ks], c[rt][1], 0, 0, 0);
            }
        }

        const float* B = bss[sidx];
        #pragma unroll
        for (int ct = 0; ct < 2; ++ct) {
            float bb = B[(wave << 5) + (ct << 4) + (lane & 15)];
            #pragma unroll
            for (int rt = 0; rt < 4; ++rt)
                #pragma unroll
                for (int q = 0; q < 4; ++q) {
                    float v = c[rt][ct][q] + bb;
                    facc[rt][ct][q] += v > 0.f ? v : 0.f;
                }
        }
    }

    #pragma unroll
    for (int rt = 0; rt < 4; ++rt)
        #pragma unroll
        for (int q = 0; q < 4; ++q) {
            int row = row0 + (rt << 4) + ((lane >> 4) << 2) + q;
            if (row >= NN) continue;
            #pragma unroll
            for (int ct = 0; ct < 2; ++ct) {
                int col = (wave << 5) + (ct << 4) + (lane & 15);
                size_t off = (size_t)row * DD + col;
                float v = facc[rt][ct][q] + xold[off];
                xnew[off] = v;
                if (WRITEB) xbnew[off] = f2b(v);
            }
        }
}

extern "C" void kernel_launch(void* const* d_in, const int* in_sizes, int n_in,
                              void* d_out, int out_size, void* d_ws, size_t ws_size,
                              hipStream_t stream) {
    const float* x0   = (const float*)d_in[0];
    const float* Ws_s = (const float*)d_in[1];
    const float* bs_s = (const float*)d_in[2];
    const float* Ws_k = (const float*)d_in[3];
    const float* bs_k = (const float*)d_in[4];
    const int*   src  = (const int*)d_in[5];
    const int*   dst  = src + NE;
    const int*   attr = (const int*)d_in[6];
    float* out = (float*)d_out;

    // workspace carve-up
    float*  x1   = (float*)d_ws;                         // 25.6 MB
    ushort* xb0  = (ushort*)(x1 + (size_t)NN * DD);      // 12.8 MB each
    ushort* xb1  = xb0 + (size_t)NN * DD;
    ushort* xb2  = xb1 + (size_t)NN * DD;
    ushort* P0   = xb2 + (size_t)NN * DD;                // agg slot (binned alias pre-gather)
    ushort* P1   = P0 + (size_t)NN * DD;                 // agg slot (hist2+off2 alias pre-gather)
    ushort* P2   = P1 + (size_t)NN * DD;                 // agg slot
    ushort* wtb  = P2 + (size_t)NN * DD;                 // 9 * 16384 * 2B
    int* ptr    = (int*)(wtb + 9 * 16384);               // 3N+1
    int* part2  = ptr + 3 * NN + 1;                      // 1024
    int* ssrc   = part2 + 1024;                          // NE ints (6 MB)
    uint* binned = (uint*)P0;                            // NE uints (6 MB), dead after finalize
    int* hist2  = (int*)P1;                              // NH2 ints (602 KB), dead after scan
    int* off2   = hist2 + NH2;                           // NH2 ints, dead after finalize

    const int gGemm = (NN + 63) / 64;
    const int gGath = (NN + 7) / 8;
    const int NB2 = (NH2 + 255) / 256;      // 588

    auto wt = [&](int m) { return wtb + (size_t)m * 16384; };
    auto bk = [&](int t, int k) { return bs_k + ((size_t)t * 3 + k) * DD; };

    // ---------- fused prologue + binning + CSR (no global atomics) ----------
    prep_all<<<BINB + GCONV + 144, 256, 0, stream>>>(
        dst, attr, hist2, x0, xb0, Ws_s, Ws_k, wtb);
    scan_block<<<NB2, 256, 0, stream>>>(hist2, off2, part2, NH2);
    scan_partials<<<1, 64, 0, stream>>>(part2, NB2);
    scan_add<<<NB2, 256, 0, stream>>>(off2, part2, NH2);
    binB<<<BINB, 256, 0, stream>>>(src, dst, attr, off2, binned);
    bucket_finalize<<<NBUCK, 256, 0, stream>>>(binned, off2, ptr, ssrc);

    // ---------- layer 0 ----------
    gather_multi<<<dim3(gGath, 1), 256, 0, stream>>>(
        xb0, nullptr, nullptr, ptr, ssrc, P0, nullptr, nullptr);
    layer_mm<2, 1><<<gGemm, 256, 0, stream>>>(
        xb0, P0, nullptr, nullptr,
        wt(0), wt(3), nullptr, nullptr,
        bs_s, bk(0, 0), nullptr, nullptr,
        x0, x1, xb1);

    // ---------- layer 1 ----------
    gather_multi<<<dim3(gGath, 2), 256, 0, stream>>>(
        xb1, xb0, nullptr, ptr, ssrc, P0, P1, nullptr);
    layer_mm<3, 1><<<gGemm, 256, 0, stream>>>(
        xb1, P0, P1, nullptr,
        wt(1), wt(4), wt(5), nullptr,
        bs_s + DD, bk(1, 0), bk(1, 1), nullptr,
        x1, out, xb2);                      // x2 lives in d_out

    // ---------- layer 2 ----------
    gather_multi<<<dim3(gGath, 3), 256, 0, stream>>>(
        xb2, xb1, xb0, ptr, ssrc, P0, P1, P2);
    layer_mm<4, 0><<<gGemm, 256, 0, stream>>>(
        xb2, P0, P1, P2,
        wt(2), wt(6), wt(7), wt(8),
        bs_s + 2 * DD, bk(2, 0), bk(2, 1), bk(2, 2),
        out, out, nullptr);                 // x3 overwrites x2 in d_out
}

// Round 11
// 267.194 us; speedup vs baseline: 1.1172x; 1.0332x over previous
//
#include <hip/hip_runtime.h>

#define NN 50000
#define NE 1500000
#define DD 128
#define NRANGE ((NN + 255) / 256)      // 196 dst-ranges of 256 nodes
#define NBUCK (3 * NRANGE)             // 588 (rel, range) buckets
#define BINB 512                       // binning blocks (2 per CU)
#define CHUNK ((NE + BINB - 1) / BINB) // 2930 edges per binning block
#define NH2 (NBUCK * BINB)             // 301056 hist2 entries
#define GCONV ((NN * DD / 4 + 255) / 256)  // 6250 to_bf16 blocks

typedef __attribute__((ext_vector_type(8))) short short8;
typedef __attribute__((ext_vector_type(4))) float f32x4;

__device__ __forceinline__ ushort f2b(float x) {
    uint u = __float_as_uint(x);
    u += 0x7FFFu + ((u >> 16) & 1u);
    return (ushort)(u >> 16);
}
__device__ __forceinline__ float b2f(ushort b) {
    return __uint_as_float(((uint)b) << 16);
}

// ---------------- scan helpers ----------------
__global__ __launch_bounds__(256) void scan_block(
    const int* __restrict__ cnt, int* __restrict__ ptr, int* __restrict__ part, int n)
{
    __shared__ int s[256];
    int i = blockIdx.x * 256 + threadIdx.x;
    int v = (i < n) ? cnt[i] : 0;
    s[threadIdx.x] = v;
    __syncthreads();
    #pragma unroll
    for (int off = 1; off < 256; off <<= 1) {
        int t = (threadIdx.x >= off) ? s[threadIdx.x - off] : 0;
        __syncthreads();
        s[threadIdx.x] += t;
        __syncthreads();
    }
    if (i < n) ptr[i] = s[threadIdx.x] - v;
    if (threadIdx.x == 255) part[blockIdx.x] = s[255];
}

__global__ void scan_partials(int* __restrict__ part, int nb)
{
    int lane = threadIdx.x;
    int run = 0;
    for (int base = 0; base < nb; base += 64) {
        int i = base + lane;
        int v = (i < nb) ? part[i] : 0;
        int x = v;
        #pragma unroll
        for (int off = 1; off < 64; off <<= 1) {
            int t = __shfl_up(x, off);
            if (lane >= off) x += t;
        }
        if (i < nb) part[i] = run + x - v;
        run += __shfl(x, 63);
    }
}

__global__ __launch_bounds__(256) void scan_add(
    int* __restrict__ ptr, const int* __restrict__ part, int n)
{
    int i = blockIdx.x * 256 + threadIdx.x;
    if (i >= n) return;
    ptr[i] += part[blockIdx.x];
}

// ---------------- fused prologue: histB | to_bf16 | prep_w ----------------
__global__ __launch_bounds__(256) void prep_all(
    const int* __restrict__ dst, const int* __restrict__ attr, int* __restrict__ hist2,
    const float* __restrict__ x, ushort* __restrict__ xb,
    const float* __restrict__ Ws_s, const float* __restrict__ Ws_k, ushort* __restrict__ wt)
{
    __shared__ int lh[NBUCK];
    int b = blockIdx.x, tid = threadIdx.x;
    if (b < BINB) {
        for (int i = tid; i < NBUCK; i += 256) lh[i] = 0;
        __syncthreads();
        int lo = b * CHUNK, hi = lo + CHUNK; if (hi > NE) hi = NE;
        for (int e = lo + tid; e < hi; e += 256)
            atomicAdd(&lh[attr[e] * NRANGE + (dst[e] >> 8)], 1);
        __syncthreads();
        for (int i = tid; i < NBUCK; i += 256) hist2[i * BINB + b] = lh[i];
    } else if (b < BINB + GCONV) {
        int i = (b - BINB) * 256 + tid;
        if (i < NN * DD / 4) {
            float4 v = ((const float4*)x)[i];
            ushort4 o;
            o.x = f2b(v.x); o.y = f2b(v.y); o.z = f2b(v.z); o.w = f2b(v.w);
            ((ushort4*)xb)[i] = o;
        }
    } else {
        int i = (b - BINB - GCONV) * 256 + tid;
        if (i < 9 * 4096) {
            int m = i >> 12;
            int f = (i & 4095) * 4;
            int k = f >> 7, n = f & 127;
            const int tk[6] = {0, 3, 4, 6, 7, 8};
            const float* W = (m < 3) ? (Ws_s + (size_t)m * 16384)
                                     : (Ws_k + (size_t)tk[m - 3] * 16384);
            float4 v = *(const float4*)(W + (size_t)k * DD + n);
            ushort* o = wt + (size_t)m * 16384 + k;
            o[(size_t)(n + 0) * DD] = f2b(v.x);
            o[(size_t)(n + 1) * DD] = f2b(v.y);
            o[(size_t)(n + 2) * DD] = f2b(v.z);
            o[(size_t)(n + 3) * DD] = f2b(v.w);
        }
    }
}

// ---------------- contention-free binning ----------------
__global__ __launch_bounds__(256) void binB(
    const int* __restrict__ src, const int* __restrict__ dst, const int* __restrict__ attr,
    const int* __restrict__ off2, uint* __restrict__ binned)
{
    __shared__ int lc[NBUCK];
    int tid = threadIdx.x, blk = blockIdx.x;
    for (int i = tid; i < NBUCK; i += 256) lc[i] = off2[i * BINB + blk];
    __syncthreads();
    int lo = blk * CHUNK, hi = lo + CHUNK; if (hi > NE) hi = NE;
    for (int e = lo + tid; e < hi; e += 256) {
        int d = dst[e];
        int b = attr[e] * NRANGE + (d >> 8);
        int pos = atomicAdd(&lc[b], 1);
        binned[pos] = (uint)src[e] | ((uint)(d & 255) << 16);   // src < 2^16
    }
}

// per-bucket: derive per-node CSR ptr (LDS hist+scan) and place edges into ssrc
__global__ __launch_bounds__(256) void bucket_finalize(
    const uint* __restrict__ binned, const int* __restrict__ off2,
    int* __restrict__ ptr, int* __restrict__ ssrc)
{
    __shared__ int lh[256];
    __shared__ int sc[256];
    __shared__ int cur[256];
    int b = blockIdx.x, tid = threadIdx.x;
    int rel = b / NRANGE, r0 = (b % NRANGE) << 8;
    int nloc = NN - r0; if (nloc > 256) nloc = 256;
    int lo = off2[b * BINB];
    int hi = (b + 1 < NBUCK) ? off2[(b + 1) * BINB] : NE;
    lh[tid] = 0;
    __syncthreads();
    for (int e = lo + tid; e < hi; e += 256)
        atomicAdd(&lh[(binned[e] >> 16) & 255], 1);
    __syncthreads();
    int v = lh[tid];
    sc[tid] = v;
    __syncthreads();
    #pragma unroll
    for (int off = 1; off < 256; off <<= 1) {
        int t = (tid >= off) ? sc[tid - off] : 0;
        __syncthreads();
        sc[tid] += t;
        __syncthreads();
    }
    int excl = lo + sc[tid] - v;
    if (tid < nloc) ptr[rel * NN + r0 + tid] = excl;
    cur[tid] = excl;
    if (b == NBUCK - 1 && tid == 0) ptr[3 * NN] = NE;
    __syncthreads();
    for (int e = lo + tid; e < hi; e += 256) {
        uint p = binned[e];
        int pos = atomicAdd(&cur[(p >> 16) & 255], 1);
        ssrc[pos] = (int)(p & 0xFFFFu);
    }
}

// ---------------- layer-grouped gather, 2 nodes per wave -------------------
__global__ __launch_bounds__(256) void gather_multi(
    const ushort* __restrict__ h0, const ushort* __restrict__ h1,
    const ushort* __restrict__ h2,
    const int* __restrict__ ptr, const int* __restrict__ ssrc,
    ushort* __restrict__ a0, ushort* __restrict__ a1, ushort* __restrict__ a2)
{
    int rel = blockIdx.y;
    const ushort* h = (rel == 0) ? h0 : ((rel == 1) ? h1 : h2);
    ushort* agg     = (rel == 0) ? a0 : ((rel == 1) ? a1 : a2);

    int tid  = threadIdx.x;
    int half = (tid >> 5) & 1;
    int sub  = tid & 31;
    int n = blockIdx.x * 8 + ((tid >> 6) << 1) + half;
    if (n >= NN) return;
    const int* p = ptr + rel * NN + n;
    int s0 = p[0], s1 = p[1];          // broadcast within half-wave
    float A0 = 0.f, A1 = 0.f, A2 = 0.f, A3 = 0.f;
    int e = s0;
    for (; e + 8 <= s1; e += 8) {
        int idx[8];
        #pragma unroll
        for (int j = 0; j < 8; ++j) idx[j] = ssrc[e + j];
        uint2 v[8];
        #pragma unroll
        for (int j = 0; j < 8; ++j)
            v[j] = ((const uint2*)(h + (size_t)idx[j] * DD))[sub];
        #pragma unroll
        for (int j = 0; j < 8; ++j) {
            A0 += b2f((ushort)(v[j].x & 0xFFFFu)); A1 += b2f((ushort)(v[j].x >> 16));
            A2 += b2f((ushort)(v[j].y & 0xFFFFu)); A3 += b2f((ushort)(v[j].y >> 16));
        }
    }
    if (e + 4 <= s1) {
        int i0 = ssrc[e], i1 = ssrc[e + 1], i2 = ssrc[e + 2], i3 = ssrc[e + 3];
        uint2 v0 = ((const uint2*)(h + (size_t)i0 * DD))[sub];
        uint2 v1 = ((const uint2*)(h + (size_t)i1 * DD))[sub];
        uint2 v2 = ((const uint2*)(h + (size_t)i2 * DD))[sub];
        uint2 v3 = ((const uint2*)(h + (size_t)i3 * DD))[sub];
        A0 += b2f((ushort)(v0.x & 0xFFFFu)); A1 += b2f((ushort)(v0.x >> 16));
        A2 += b2f((ushort)(v0.y & 0xFFFFu)); A3 += b2f((ushort)(v0.y >> 16));
        A0 += b2f((ushort)(v1.x & 0xFFFFu)); A1 += b2f((ushort)(v1.x >> 16));
        A2 += b2f((ushort)(v1.y & 0xFFFFu)); A3 += b2f((ushort)(v1.y >> 16));
        A0 += b2f((ushort)(v2.x & 0xFFFFu)); A1 += b2f((ushort)(v2.x >> 16));
        A2 += b2f((ushort)(v2.y & 0xFFFFu)); A3 += b2f((ushort)(v2.y >> 16));
        A0 += b2f((ushort)(v3.x & 0xFFFFu)); A1 += b2f((ushort)(v3.x >> 16));
        A2 += b2f((ushort)(v3.y & 0xFFFFu)); A3 += b2f((ushort)(v3.y >> 16));
        e += 4;
    }
    for (; e < s1; ++e) {
        int s = ssrc[e];
        uint2 v = ((const uint2*)(h + (size_t)s * DD))[sub];
        A0 += b2f((ushort)(v.x & 0xFFFFu)); A1 += b2f((ushort)(v.x >> 16));
        A2 += b2f((ushort)(v.y & 0xFFFFu)); A3 += b2f((ushort)(v.y >> 16));
    }
    uint2 o;
    o.x = (uint)f2b(A0) | ((uint)f2b(A1) << 16);
    o.y = (uint)f2b(A2) | ((uint)f2b(A3) << 16);
    ((uint2*)(agg + (size_t)n * DD))[sub] = o;
}

// ---------------- fused layer: x_new = x_old + sum_s relu(A_s @ W_s + b_s) ----
// Residual kept in bf16 (xoldb); f32 output written only for final layer.
template<int NSRC, int WRITEF>
__global__ __launch_bounds__(256) void layer_mm(
    const ushort* __restrict__ s0, const ushort* __restrict__ s1,
    const ushort* __restrict__ s2, const ushort* __restrict__ s3,
    const ushort* __restrict__ w0, const ushort* __restrict__ w1,
    const ushort* __restrict__ w2, const ushort* __restrict__ w3,
    const float* __restrict__ b0, const float* __restrict__ b1,
    const float* __restrict__ b2, const float* __restrict__ b3,
    const ushort* __restrict__ xoldb, float* __restrict__ xnewf, ushort* __restrict__ xbnew)
{
    __shared__ ushort Atile[64 * 128];   // XOR-swizzled
    const int tid  = threadIdx.x;
    const int wave = tid >> 6, lane = tid & 63;
    const int row0 = blockIdx.x * 64;

    const ushort* srcs[4] = { s0, s1, s2, s3 };
    const ushort* wts[4]  = { w0, w1, w2, w3 };
    const float*  bss[4]  = { b0, b1, b2, b3 };

    float facc[4][2][4];
    #pragma unroll
    for (int rt = 0; rt < 4; ++rt)
        #pragma unroll
        for (int ct = 0; ct < 2; ++ct)
            #pragma unroll
            for (int q = 0; q < 4; ++q) facc[rt][ct][q] = 0.f;

    #pragma unroll
    for (int sidx = 0; sidx < NSRC; ++sidx) {
        const ushort* S = srcs[sidx];
        const ushort* W = wts[sidx];

        __syncthreads();
        for (int i = tid; i < 1024; i += 256) {
            int r = i >> 4, c = i & 15;
            int gr = row0 + r;
            uint4 v = make_uint4(0, 0, 0, 0);
            if (gr < NN) v = ((const uint4*)(S + (size_t)gr * DD))[c];
            int byte = ((r << 8) + (c << 4)) ^ ((r & 7) << 4);
            *((uint4*)((char*)Atile + byte)) = v;
        }
        short8 bfr[2][4];
        #pragma unroll
        for (int ct = 0; ct < 2; ++ct)
            #pragma unroll
            for (int ks = 0; ks < 4; ++ks) {
                int col = (wave << 5) + (ct << 4) + (lane & 15);
                int kb  = (ks << 5) + ((lane >> 4) << 3);
                bfr[ct][ks] = *(const short8*)(W + (size_t)col * DD + kb);
            }
        __syncthreads();

        f32x4 c[4][2];
        #pragma unroll
        for (int rt = 0; rt < 4; ++rt)
            #pragma unroll
            for (int ct = 0; ct < 2; ++ct) c[rt][ct] = (f32x4)(0.f);

        #pragma unroll
        for (int rt = 0; rt < 4; ++rt) {
            int row = (rt << 4) + (lane & 15);
            #pragma unroll
            for (int ks = 0; ks < 4; ++ks) {
                int byte = ((row << 8) + (ks << 6) + ((lane >> 4) << 4)) ^ ((row & 7) << 4);
                short8 a = *((const short8*)((const char*)Atile + byte));
                c[rt][0] = __builtin_amdgcn_mfma_f32_16x16x32_bf16(a, bfr[0][ks], c[rt][0], 0, 0, 0);
                c[rt][1] = __builtin_amdgcn_mfma_f32_16x16x32_bf16(a, bfr[1][ks], c[rt][1], 0, 0, 0);
            }
        }

        const float* B = bss[sidx];
        #pragma unroll
        for (int ct = 0; ct < 2; ++ct) {
            float bb = B[(wave << 5) + (ct << 4) + (lane & 15)];
            #pragma unroll
            for (int rt = 0; rt < 4; ++rt)
                #pragma unroll
                for (int q = 0; q < 4; ++q) {
                    float v = c[rt][ct][q] + bb;
                    facc[rt][ct][q] += v > 0.f ? v : 0.f;
                }
        }
    }

    #pragma unroll
    for (int rt = 0; rt < 4; ++rt)
        #pragma unroll
        for (int q = 0; q < 4; ++q) {
            int row = row0 + (rt << 4) + ((lane >> 4) << 2) + q;
            if (row >= NN) continue;
            #pragma unroll
            for (int ct = 0; ct < 2; ++ct) {
                int col = (wave << 5) + (ct << 4) + (lane & 15);
                size_t off = (size_t)row * DD + col;
                float v = facc[rt][ct][q] + b2f(xoldb[off]);
                xbnew[off] = f2b(v);
                if (WRITEF) xnewf[off] = v;
            }
        }
}

extern "C" void kernel_launch(void* const* d_in, const int* in_sizes, int n_in,
                              void* d_out, int out_size, void* d_ws, size_t ws_size,
                              hipStream_t stream) {
    const float* x0   = (const float*)d_in[0];
    const float* Ws_s = (const float*)d_in[1];
    const float* bs_s = (const float*)d_in[2];
    const float* Ws_k = (const float*)d_in[3];
    const float* bs_k = (const float*)d_in[4];
    const int*   src  = (const int*)d_in[5];
    const int*   dst  = src + NE;
    const int*   attr = (const int*)d_in[6];
    float* out = (float*)d_out;

    // workspace carve-up
    ushort* xb0  = (ushort*)d_ws;                        // 12.8 MB each
    ushort* xb1  = xb0 + (size_t)NN * DD;
    ushort* xb2  = xb1 + (size_t)NN * DD;
    ushort* xb3  = xb2 + (size_t)NN * DD;                // scratch bf16 copy of x3
    ushort* P0   = xb3 + (size_t)NN * DD;                // agg slot (binned alias pre-gather)
    ushort* P1   = P0 + (size_t)NN * DD;                 // agg slot (hist2+off2 alias pre-gather)
    ushort* P2   = P1 + (size_t)NN * DD;                 // agg slot
    ushort* wtb  = P2 + (size_t)NN * DD;                 // 9 * 16384 * 2B
    int* ptr    = (int*)(wtb + 9 * 16384);               // 3N+1
    int* part2  = ptr + 3 * NN + 1;                      // 2048
    int* ssrc   = part2 + 2048;                          // NE ints (6 MB)
    uint* binned = (uint*)P0;                            // NE uints (6 MB), dead after finalize
    int* hist2  = (int*)P1;                              // NH2 ints (1.2 MB), dead after scan
    int* off2   = hist2 + NH2;                           // NH2 ints, dead after finalize

    const int gGemm = (NN + 63) / 64;
    const int gGath = (NN + 7) / 8;
    const int NB2 = (NH2 + 255) / 256;      // 1176

    auto wt = [&](int m) { return wtb + (size_t)m * 16384; };
    auto bk = [&](int t, int k) { return bs_k + ((size_t)t * 3 + k) * DD; };

    // ---------- fused prologue + binning + CSR (no global atomics) ----------
    prep_all<<<BINB + GCONV + 144, 256, 0, stream>>>(
        dst, attr, hist2, x0, xb0, Ws_s, Ws_k, wtb);
    scan_block<<<NB2, 256, 0, stream>>>(hist2, off2, part2, NH2);
    scan_partials<<<1, 64, 0, stream>>>(part2, NB2);
    scan_add<<<NB2, 256, 0, stream>>>(off2, part2, NH2);
    binB<<<BINB, 256, 0, stream>>>(src, dst, attr, off2, binned);
    bucket_finalize<<<NBUCK, 256, 0, stream>>>(binned, off2, ptr, ssrc);

    // ---------- layer 0 ----------
    gather_multi<<<dim3(gGath, 1), 256, 0, stream>>>(
        xb0, nullptr, nullptr, ptr, ssrc, P0, nullptr, nullptr);
    layer_mm<2, 0><<<gGemm, 256, 0, stream>>>(
        xb0, P0, nullptr, nullptr,
        wt(0), wt(3), nullptr, nullptr,
        bs_s, bk(0, 0), nullptr, nullptr,
        xb0, nullptr, xb1);

    // ---------- layer 1 ----------
    gather_multi<<<dim3(gGath, 2), 256, 0, stream>>>(
        xb1, xb0, nullptr, ptr, ssrc, P0, P1, nullptr);
    layer_mm<3, 0><<<gGemm, 256, 0, stream>>>(
        xb1, P0, P1, nullptr,
        wt(1), wt(4), wt(5), nullptr,
        bs_s + DD, bk(1, 0), bk(1, 1), nullptr,
        xb1, nullptr, xb2);

    // ---------- layer 2 ----------
    gather_multi<<<dim3(gGath, 3), 256, 0, stream>>>(
        xb2, xb1, xb0, ptr, ssrc, P0, P1, P2);
    layer_mm<4, 1><<<gGemm, 256, 0, stream>>>(
        xb2, P0, P1, P2,
        wt(2), wt(6), wt(7), wt(8),
        bs_s + 2 * DD, bk(2, 0), bk(2, 1), bk(2, 2),
        xb2, out, xb3);
}